// Round 2
// baseline (170.841 us; speedup 1.0000x reference)
//
#include <hip/hip_runtime.h>

#define BATCH 8
#define CCH 8
#define HW 262144       // 512*512
#define SEGS 16         // segments 1..16 (segment 0 is provably ignored by the reference)
#define NREP 16         // one accumulator replica per 16-lane group
#define RSTRIDE 132     // replica stride in floats: 132%32=4 -> 4-bank rotation per replica
#define CSTRIDE 17      // count replica stride: bank rotation 17%32

// ws float layout:
//   [0, 128)      counts[b][s]
//   [128, 1152)   sums[b][s][c]
//   [1152, 1280)  pen_sum[b][s]

__global__ __launch_bounds__(256) void accum_kernel(
    const float* __restrict__ emb, const int* __restrict__ lab,
    const int* __restrict__ msk, float* __restrict__ ws)
{
    const int b = blockIdx.y;
    const int rep = threadIdx.x >> 4;            // 16 replicas per block
    __shared__ float lsum[NREP * RSTRIDE];       // slot: rep*RSTRIDE + c*16 + s
    __shared__ float lcnt[NREP * CSTRIDE];       // slot: rep*CSTRIDE + s
    for (int i = threadIdx.x; i < NREP * RSTRIDE; i += 256) lsum[i] = 0.f;
    for (int i = threadIdx.x; i < NREP * CSTRIDE; i += 256) lcnt[i] = 0.f;
    __syncthreads();

    const float* eb = emb + (size_t)b * CCH * HW;
    const int g = blockIdx.x * 256 + threadIdx.x;   // 256*256 threads == HW/4 quads
    int4 l4 = ((const int4*)(lab + (size_t)b * HW))[g];
    int4 m4 = ((const int4*)(msk + (size_t)b * HW))[g];
    int id[4];
    id[0] = m4.x ? l4.x : 0;
    id[1] = m4.y ? l4.y : 0;
    id[2] = m4.z ? l4.z : 0;
    id[3] = m4.w ? l4.w : 0;

    float* ls = lsum + rep * RSTRIDE;
    float* lc = lcnt + rep * CSTRIDE;
#pragma unroll
    for (int j = 0; j < 4; ++j)
        if (id[j]) atomicAdd(&lc[id[j] - 1], 1.0f);
#pragma unroll
    for (int c = 0; c < CCH; ++c) {
        float4 e4 = ((const float4*)(eb + (size_t)c * HW))[g];
        float ev[4] = {e4.x, e4.y, e4.z, e4.w};
#pragma unroll
        for (int j = 0; j < 4; ++j)
            if (id[j]) atomicAdd(&ls[c * SEGS + id[j] - 1], ev[j]);
    }
    __syncthreads();

    // flush: slot i = c*16+s -> ws[128 + b*128 + s*CCH + c]
    if (threadIdx.x < SEGS * CCH) {
        const int i = threadIdx.x;
        const int c = i >> 4, s = i & 15;
        float v = 0.f;
#pragma unroll
        for (int r = 0; r < NREP; ++r) v += lsum[r * RSTRIDE + i];
        if (v != 0.f) atomicAdd(&ws[128 + (b * SEGS + s) * CCH + c], v);
    } else if (threadIdx.x < SEGS * CCH + SEGS) {
        const int s = threadIdx.x - SEGS * CCH;
        float v = 0.f;
#pragma unroll
        for (int r = 0; r < NREP; ++r) v += lcnt[r * CSTRIDE + s];
        if (v != 0.f) atomicAdd(&ws[b * SEGS + s], v);
    }
}

__global__ __launch_bounds__(256) void pull_kernel(
    const float* __restrict__ emb, const int* __restrict__ lab,
    const int* __restrict__ msk, float* __restrict__ ws)
{
    const int b = blockIdx.y;
    const int rep = threadIdx.x >> 4;
    __shared__ float mt[CCH][SEGS];              // transposed means: divergent reads hit 16 banks
    __shared__ float lpen[NREP * CSTRIDE];
    for (int i = threadIdx.x; i < NREP * CSTRIDE; i += 256) lpen[i] = 0.f;
    if (threadIdx.x < SEGS * CCH) {
        int s = threadIdx.x & (SEGS - 1);
        int c = threadIdx.x >> 4;
        float cnt = ws[b * SEGS + s];
        mt[c][s] = ws[128 + (b * SEGS + s) * CCH + c] / fmaxf(cnt, 1.0f);
    }
    __syncthreads();

    const float* eb = emb + (size_t)b * CCH * HW;
    const int g = blockIdx.x * 256 + threadIdx.x;
    int4 l4 = ((const int4*)(lab + (size_t)b * HW))[g];
    int4 m4 = ((const int4*)(msk + (size_t)b * HW))[g];
    int id[4];
    id[0] = m4.x ? l4.x : 0;
    id[1] = m4.y ? l4.y : 0;
    id[2] = m4.z ? l4.z : 0;
    id[3] = m4.w ? l4.w : 0;
    int ix[4];
#pragma unroll
    for (int j = 0; j < 4; ++j) ix[j] = id[j] ? id[j] - 1 : 0;

    float ss[4] = {0.f, 0.f, 0.f, 0.f};
#pragma unroll
    for (int c = 0; c < CCH; ++c) {
        float4 e4 = ((const float4*)(eb + (size_t)c * HW))[g];
        float ev[4] = {e4.x, e4.y, e4.z, e4.w};
#pragma unroll
        for (int j = 0; j < 4; ++j) {
            float d = ev[j] - mt[c][ix[j]];
            ss[j] += d * d;
        }
    }
    float* lp = lpen + rep * CSTRIDE;
#pragma unroll
    for (int j = 0; j < 4; ++j) {
        if (id[j]) {
            float d = sqrtf(fmaxf(ss[j], 1e-12f));
            float h = fmaxf(d - 0.5f, 0.f);
            atomicAdd(&lp[ix[j]], h * h);
        }
    }
    __syncthreads();
    if (threadIdx.x < SEGS) {
        const int s = threadIdx.x;
        float v = 0.f;
#pragma unroll
        for (int r = 0; r < NREP; ++r) v += lpen[r * CSTRIDE + s];
        if (v != 0.f) atomicAdd(&ws[1152 + b * SEGS + s], v);
    }
}

__global__ __launch_bounds__(256) void finalize_kernel(
    const float* __restrict__ ws, float* __restrict__ out)
{
    __shared__ float cnt[BATCH][SEGS];
    __shared__ float mu[BATCH][SEGS][CCH];
    __shared__ float pen[BATCH][SEGS];
    __shared__ float res[BATCH][3];

    for (int i = threadIdx.x; i < BATCH * SEGS; i += 256) {
        (&cnt[0][0])[i] = ws[i];
        (&pen[0][0])[i] = ws[1152 + i];
    }
    for (int i = threadIdx.x; i < BATCH * SEGS * CCH; i += 256) {
        float c = ws[i / CCH];
        (&mu[0][0][0])[i] = ws[128 + i] / fmaxf(c, 1.0f);
    }
    __syncthreads();

    const int b = threadIdx.x >> 5;   // 8 batches x 32-lane groups
    const int l = threadIdx.x & 31;

    float pullv = 0.f, Kf = 0.f;
    if (l < SEGS && cnt[b][l] > 0.f) {
        Kf = 1.f;
        pullv = pen[b][l] / cnt[b][l];
    }
    float hs = 0.f, np = 0.f;
    for (int p = l; p < 256; p += 32) {
        int i = p >> 4, j = p & 15;
        if (i < j && cnt[b][i] > 0.f && cnt[b][j] > 0.f) {
            float ssq = 0.f;
#pragma unroll
            for (int c = 0; c < CCH; ++c) {
                float d = mu[b][i][c] - mu[b][j][c];
                ssq += d * d;
            }
            float dist = sqrtf(fmaxf(ssq, 1e-12f));
            float h = fmaxf(3.0f - dist, 0.f);   // 2*DELTA_D = 3.0
            hs += h * h;
            np += 1.f;
        }
    }
#pragma unroll
    for (int m = 16; m >= 1; m >>= 1) {
        pullv += __shfl_xor(pullv, m);
        Kf    += __shfl_xor(Kf, m);
        hs    += __shfl_xor(hs, m);
        np    += __shfl_xor(np, m);
    }
    if (l == 0) {
        res[b][0] = (Kf > 0.f) ? pullv / Kf : 0.f;
        res[b][1] = (np > 0.f) ? hs / np : 0.f;
        res[b][2] = (Kf > 0.f) ? 1.f : 0.f;
    }
    __syncthreads();
    if (threadIdx.x == 0) {
        float sp = 0.f, sh = 0.f, nv = 0.f;
        for (int bb = 0; bb < BATCH; ++bb) {
            sp += res[bb][0] * res[bb][2];
            sh += res[bb][1] * res[bb][2];
            nv += res[bb][2];
        }
        nv = fmaxf(nv, 1.f);
        out[0] = sp / nv;
        out[1] = sh / nv;
    }
}

extern "C" void kernel_launch(void* const* d_in, const int* in_sizes, int n_in,
                              void* d_out, int out_size, void* d_ws, size_t ws_size,
                              hipStream_t stream)
{
    const float* emb = (const float*)d_in[0];
    const int* lab = (const int*)d_in[1];
    const int* msk = (const int*)d_in[2];
    float* out = (float*)d_out;
    float* ws = (float*)d_ws;

    hipMemsetAsync(d_ws, 0, 1280 * sizeof(float), stream);
    dim3 grid(256, BATCH);   // 256*256 threads per batch slice == HW/4 quads, 1 quad/thread
    accum_kernel<<<grid, 256, 0, stream>>>(emb, lab, msk, ws);
    pull_kernel<<<grid, 256, 0, stream>>>(emb, lab, msk, ws);
    finalize_kernel<<<1, 256, 0, stream>>>(ws, out);
}

// Round 3
// 159.160 us; speedup vs baseline: 1.0734x; 1.0734x over previous
//
#include <hip/hip_runtime.h>

#define BATCH 8
#define CCH 8
#define HW 262144       // 512*512
#define SEGS 16         // segments 1..16 (segment 0 is provably ignored by the reference)
#define GX 128          // grid.x; each thread handles 2 quads

// ws float layout:
//   [0, 128)      counts[b][s]
//   [128, 1152)   sums[b][s][c]
//   [1152, 1280)  pen_sum[b][s]

__global__ __launch_bounds__(256) void accum_kernel(
    const float* __restrict__ emb, const int* __restrict__ lab,
    const int* __restrict__ msk, float* __restrict__ ws)
{
    const int b = blockIdx.y;
    const int wave = threadIdx.x >> 6;
    // stride-9 pad: for fixed c, addresses s*9+c hit 16 distinct banks (9 coprime 32)
    __shared__ float lsum[4][SEGS][9];
    __shared__ float lcnt[4][SEGS + 1];
    for (int i = threadIdx.x; i < 4 * SEGS * 9; i += 256) (&lsum[0][0][0])[i] = 0.f;
    for (int i = threadIdx.x; i < 4 * (SEGS + 1); i += 256) (&lcnt[0][0])[i] = 0.f;
    __syncthreads();

    const float* ebase = emb + (size_t)b * CCH * HW;
    const int4* lb = (const int4*)(lab + (size_t)b * HW);
    const int4* mb = (const int4*)(msk + (size_t)b * HW);

    const int g0 = blockIdx.x * 256 + threadIdx.x;
    const int g1 = g0 + GX * 256;

    // ---- batch ALL global loads before any LDS op (keep ~20 loads in flight) ----
    int4 l40 = lb[g0], l41 = lb[g1];
    int4 m40 = mb[g0], m41 = mb[g1];
    float4 e0[CCH], e1[CCH];
#pragma unroll
    for (int c = 0; c < CCH; ++c) {
        const float4* p = (const float4*)(ebase + (size_t)c * HW);
        e0[c] = p[g0];
        e1[c] = p[g1];
    }

    int id0[4], id1[4];
    id0[0] = m40.x ? l40.x : 0;  id0[1] = m40.y ? l40.y : 0;
    id0[2] = m40.z ? l40.z : 0;  id0[3] = m40.w ? l40.w : 0;
    id1[0] = m41.x ? l41.x : 0;  id1[1] = m41.y ? l41.y : 0;
    id1[2] = m41.z ? l41.z : 0;  id1[3] = m41.w ? l41.w : 0;

    float* ls = &lsum[wave][0][0];
    float* lc = &lcnt[wave][0];
#pragma unroll
    for (int j = 0; j < 4; ++j) {
        if (id0[j]) atomicAdd(&lc[id0[j] - 1], 1.0f);
        if (id1[j]) atomicAdd(&lc[id1[j] - 1], 1.0f);
    }
#pragma unroll
    for (int c = 0; c < CCH; ++c) {
#pragma unroll
        for (int j = 0; j < 4; ++j) {
            if (id0[j]) atomicAdd(&ls[(id0[j] - 1) * 9 + c], ((const float*)&e0[c])[j]);
            if (id1[j]) atomicAdd(&ls[(id1[j] - 1) * 9 + c], ((const float*)&e1[c])[j]);
        }
    }
    __syncthreads();

    if (threadIdx.x < SEGS * CCH) {
        const int s = threadIdx.x >> 3, c = threadIdx.x & 7;
        float v = lsum[0][s][c] + lsum[1][s][c] + lsum[2][s][c] + lsum[3][s][c];
        if (v != 0.f) atomicAdd(&ws[128 + (b * SEGS + s) * CCH + c], v);
    } else if (threadIdx.x < SEGS * CCH + SEGS) {
        const int s = threadIdx.x - SEGS * CCH;
        float v = lcnt[0][s] + lcnt[1][s] + lcnt[2][s] + lcnt[3][s];
        if (v != 0.f) atomicAdd(&ws[b * SEGS + s], v);
    }
}

__global__ __launch_bounds__(256) void pull_kernel(
    const float* __restrict__ emb, const int* __restrict__ lab,
    const int* __restrict__ msk, float* __restrict__ ws)
{
    const int b = blockIdx.y;
    const int grp = (threadIdx.x >> 4) & 3;   // 16-lane group within the wave
    // 4 replicas of transposed means, stride 17: the 4 groups' gathers cover all
    // 32 banks at exactly 2 lanes/bank (2-way is free, m136)
    __shared__ float mtr[4][CCH][SEGS + 1];
    __shared__ float lpen[4][SEGS + 1];
    for (int i = threadIdx.x; i < 4 * (SEGS + 1); i += 256) (&lpen[0][0])[i] = 0.f;
    if (threadIdx.x < SEGS * CCH) {
        const int s = threadIdx.x & 15, c = threadIdx.x >> 4;
        float cnt = ws[b * SEGS + s];
        float m = ws[128 + (b * SEGS + s) * CCH + c] / fmaxf(cnt, 1.0f);
        mtr[0][c][s] = m; mtr[1][c][s] = m; mtr[2][c][s] = m; mtr[3][c][s] = m;
    }
    __syncthreads();

    const float* ebase = emb + (size_t)b * CCH * HW;
    const int4* lb = (const int4*)(lab + (size_t)b * HW);
    const int4* mb = (const int4*)(msk + (size_t)b * HW);

    const int g0 = blockIdx.x * 256 + threadIdx.x;
    const int g1 = g0 + GX * 256;

    int4 l40 = lb[g0], l41 = lb[g1];
    int4 m40 = mb[g0], m41 = mb[g1];
    float4 e0[CCH], e1[CCH];
#pragma unroll
    for (int c = 0; c < CCH; ++c) {
        const float4* p = (const float4*)(ebase + (size_t)c * HW);
        e0[c] = p[g0];
        e1[c] = p[g1];
    }

    int id0[4], id1[4];
    id0[0] = m40.x ? l40.x : 0;  id0[1] = m40.y ? l40.y : 0;
    id0[2] = m40.z ? l40.z : 0;  id0[3] = m40.w ? l40.w : 0;
    id1[0] = m41.x ? l41.x : 0;  id1[1] = m41.y ? l41.y : 0;
    id1[2] = m41.z ? l41.z : 0;  id1[3] = m41.w ? l41.w : 0;
    int ix0[4], ix1[4];
#pragma unroll
    for (int j = 0; j < 4; ++j) {
        ix0[j] = id0[j] ? id0[j] - 1 : 0;
        ix1[j] = id1[j] ? id1[j] - 1 : 0;
    }

    const float (*mt)[SEGS + 1] = mtr[grp];
    float ss0[4] = {0.f, 0.f, 0.f, 0.f};
    float ss1[4] = {0.f, 0.f, 0.f, 0.f};
#pragma unroll
    for (int c = 0; c < CCH; ++c) {
#pragma unroll
        for (int j = 0; j < 4; ++j) {
            float d0 = ((const float*)&e0[c])[j] - mt[c][ix0[j]];
            ss0[j] += d0 * d0;
            float d1 = ((const float*)&e1[c])[j] - mt[c][ix1[j]];
            ss1[j] += d1 * d1;
        }
    }
    float* lp = &lpen[grp][0];
#pragma unroll
    for (int j = 0; j < 4; ++j) {
        if (id0[j]) {
            float d = sqrtf(fmaxf(ss0[j], 1e-12f));
            float h = fmaxf(d - 0.5f, 0.f);
            atomicAdd(&lp[ix0[j]], h * h);
        }
        if (id1[j]) {
            float d = sqrtf(fmaxf(ss1[j], 1e-12f));
            float h = fmaxf(d - 0.5f, 0.f);
            atomicAdd(&lp[ix1[j]], h * h);
        }
    }
    __syncthreads();
    if (threadIdx.x < SEGS) {
        const int s = threadIdx.x;
        float v = lpen[0][s] + lpen[1][s] + lpen[2][s] + lpen[3][s];
        if (v != 0.f) atomicAdd(&ws[1152 + b * SEGS + s], v);
    }
}

__global__ __launch_bounds__(256) void finalize_kernel(
    const float* __restrict__ ws, float* __restrict__ out)
{
    __shared__ float cnt[BATCH][SEGS];
    __shared__ float mu[BATCH][SEGS][CCH];
    __shared__ float pen[BATCH][SEGS];
    __shared__ float res[BATCH][3];

    for (int i = threadIdx.x; i < BATCH * SEGS; i += 256) {
        (&cnt[0][0])[i] = ws[i];
        (&pen[0][0])[i] = ws[1152 + i];
    }
    for (int i = threadIdx.x; i < BATCH * SEGS * CCH; i += 256) {
        float c = ws[i / CCH];
        (&mu[0][0][0])[i] = ws[128 + i] / fmaxf(c, 1.0f);
    }
    __syncthreads();

    const int b = threadIdx.x >> 5;   // 8 batches x 32-lane groups
    const int l = threadIdx.x & 31;

    float pullv = 0.f, Kf = 0.f;
    if (l < SEGS && cnt[b][l] > 0.f) {
        Kf = 1.f;
        pullv = pen[b][l] / cnt[b][l];
    }
    float hs = 0.f, np = 0.f;
    for (int p = l; p < 256; p += 32) {
        int i = p >> 4, j = p & 15;
        if (i < j && cnt[b][i] > 0.f && cnt[b][j] > 0.f) {
            float ssq = 0.f;
#pragma unroll
            for (int c = 0; c < CCH; ++c) {
                float d = mu[b][i][c] - mu[b][j][c];
                ssq += d * d;
            }
            float dist = sqrtf(fmaxf(ssq, 1e-12f));
            float h = fmaxf(3.0f - dist, 0.f);   // 2*DELTA_D = 3.0
            hs += h * h;
            np += 1.f;
        }
    }
#pragma unroll
    for (int m = 16; m >= 1; m >>= 1) {
        pullv += __shfl_xor(pullv, m);
        Kf    += __shfl_xor(Kf, m);
        hs    += __shfl_xor(hs, m);
        np    += __shfl_xor(np, m);
    }
    if (l == 0) {
        res[b][0] = (Kf > 0.f) ? pullv / Kf : 0.f;
        res[b][1] = (np > 0.f) ? hs / np : 0.f;
        res[b][2] = (Kf > 0.f) ? 1.f : 0.f;
    }
    __syncthreads();
    if (threadIdx.x == 0) {
        float sp = 0.f, sh = 0.f, nv = 0.f;
        for (int bb = 0; bb < BATCH; ++bb) {
            sp += res[bb][0] * res[bb][2];
            sh += res[bb][1] * res[bb][2];
            nv += res[bb][2];
        }
        nv = fmaxf(nv, 1.f);
        out[0] = sp / nv;
        out[1] = sh / nv;
    }
}

extern "C" void kernel_launch(void* const* d_in, const int* in_sizes, int n_in,
                              void* d_out, int out_size, void* d_ws, size_t ws_size,
                              hipStream_t stream)
{
    const float* emb = (const float*)d_in[0];
    const int* lab = (const int*)d_in[1];
    const int* msk = (const int*)d_in[2];
    float* out = (float*)d_out;
    float* ws = (float*)d_ws;

    hipMemsetAsync(d_ws, 0, 1280 * sizeof(float), stream);
    dim3 grid(GX, BATCH);   // 2 quads per thread, batched loads
    accum_kernel<<<grid, 256, 0, stream>>>(emb, lab, msk, ws);
    pull_kernel<<<grid, 256, 0, stream>>>(emb, lab, msk, ws);
    finalize_kernel<<<1, 256, 0, stream>>>(ws, out);
}

// Round 4
// 157.859 us; speedup vs baseline: 1.0822x; 1.0082x over previous
//
#include <hip/hip_runtime.h>

#define BATCH 8
#define CCH 8
#define HW 262144       // 512*512
#define SEGS 16         // segments 1..16 (segment 0 is provably ignored by the reference)
#define GX 128          // grid.x; each thread handles 2 quads

// Native (non-CAS) fp32 atomic add. Plain atomicAdd(float*) compiles to an
// IEEE-safe CAS retry loop without -munsafe-fp-atomics; under contention the
// retry storm serializes the whole kernel. unsafeAtomicAdd selects native
// ds_add_f32 / global_atomic_add_f32.
__device__ __forceinline__ void fadd(float* p, float v) { unsafeAtomicAdd(p, v); }

// ws float layout:
//   [0, 128)      counts[b][s]
//   [128, 1152)   sums[b][s][c]
//   [1152, 1280)  pen_sum[b][s]

__global__ __launch_bounds__(256) void accum_kernel(
    const float* __restrict__ emb, const int* __restrict__ lab,
    const int* __restrict__ msk, float* __restrict__ ws)
{
    const int b = blockIdx.y;
    const int wave = threadIdx.x >> 6;
    // stride-9 pad: for fixed c, addresses s*9+c hit 16 distinct banks (9 coprime 32)
    __shared__ float lsum[4][SEGS][9];
    __shared__ float lcnt[4][SEGS + 1];
    for (int i = threadIdx.x; i < 4 * SEGS * 9; i += 256) (&lsum[0][0][0])[i] = 0.f;
    for (int i = threadIdx.x; i < 4 * (SEGS + 1); i += 256) (&lcnt[0][0])[i] = 0.f;
    __syncthreads();

    const float* ebase = emb + (size_t)b * CCH * HW;
    const int4* lb = (const int4*)(lab + (size_t)b * HW);
    const int4* mb = (const int4*)(msk + (size_t)b * HW);

    const int g0 = blockIdx.x * 256 + threadIdx.x;
    const int g1 = g0 + GX * 256;

    // batch ALL global loads before any LDS op
    int4 l40 = lb[g0], l41 = lb[g1];
    int4 m40 = mb[g0], m41 = mb[g1];
    float4 e0[CCH], e1[CCH];
#pragma unroll
    for (int c = 0; c < CCH; ++c) {
        const float4* p = (const float4*)(ebase + (size_t)c * HW);
        e0[c] = p[g0];
        e1[c] = p[g1];
    }

    int id0[4], id1[4];
    id0[0] = m40.x ? l40.x : 0;  id0[1] = m40.y ? l40.y : 0;
    id0[2] = m40.z ? l40.z : 0;  id0[3] = m40.w ? l40.w : 0;
    id1[0] = m41.x ? l41.x : 0;  id1[1] = m41.y ? l41.y : 0;
    id1[2] = m41.z ? l41.z : 0;  id1[3] = m41.w ? l41.w : 0;

    float* ls = &lsum[wave][0][0];
    float* lc = &lcnt[wave][0];
#pragma unroll
    for (int j = 0; j < 4; ++j) {
        if (id0[j]) fadd(&lc[id0[j] - 1], 1.0f);
        if (id1[j]) fadd(&lc[id1[j] - 1], 1.0f);
    }
#pragma unroll
    for (int c = 0; c < CCH; ++c) {
#pragma unroll
        for (int j = 0; j < 4; ++j) {
            if (id0[j]) fadd(&ls[(id0[j] - 1) * 9 + c], ((const float*)&e0[c])[j]);
            if (id1[j]) fadd(&ls[(id1[j] - 1) * 9 + c], ((const float*)&e1[c])[j]);
        }
    }
    __syncthreads();

    if (threadIdx.x < SEGS * CCH) {
        const int s = threadIdx.x >> 3, c = threadIdx.x & 7;
        float v = lsum[0][s][c] + lsum[1][s][c] + lsum[2][s][c] + lsum[3][s][c];
        if (v != 0.f) fadd(&ws[128 + (b * SEGS + s) * CCH + c], v);
    } else if (threadIdx.x < SEGS * CCH + SEGS) {
        const int s = threadIdx.x - SEGS * CCH;
        float v = lcnt[0][s] + lcnt[1][s] + lcnt[2][s] + lcnt[3][s];
        if (v != 0.f) fadd(&ws[b * SEGS + s], v);
    }
}

__global__ __launch_bounds__(256) void pull_kernel(
    const float* __restrict__ emb, const int* __restrict__ lab,
    const int* __restrict__ msk, float* __restrict__ ws)
{
    const int b = blockIdx.y;
    const int grp = (threadIdx.x >> 4) & 3;   // 16-lane group within the wave
    __shared__ float mtr[4][CCH][SEGS + 1];
    __shared__ float lpen[4][SEGS + 1];
    for (int i = threadIdx.x; i < 4 * (SEGS + 1); i += 256) (&lpen[0][0])[i] = 0.f;
    if (threadIdx.x < SEGS * CCH) {
        const int s = threadIdx.x & 15, c = threadIdx.x >> 4;
        float cnt = ws[b * SEGS + s];
        float m = ws[128 + (b * SEGS + s) * CCH + c] / fmaxf(cnt, 1.0f);
        mtr[0][c][s] = m; mtr[1][c][s] = m; mtr[2][c][s] = m; mtr[3][c][s] = m;
    }
    __syncthreads();

    const float* ebase = emb + (size_t)b * CCH * HW;
    const int4* lb = (const int4*)(lab + (size_t)b * HW);
    const int4* mb = (const int4*)(msk + (size_t)b * HW);

    const int g0 = blockIdx.x * 256 + threadIdx.x;
    const int g1 = g0 + GX * 256;

    int4 l40 = lb[g0], l41 = lb[g1];
    int4 m40 = mb[g0], m41 = mb[g1];
    float4 e0[CCH], e1[CCH];
#pragma unroll
    for (int c = 0; c < CCH; ++c) {
        const float4* p = (const float4*)(ebase + (size_t)c * HW);
        e0[c] = p[g0];
        e1[c] = p[g1];
    }

    int id0[4], id1[4];
    id0[0] = m40.x ? l40.x : 0;  id0[1] = m40.y ? l40.y : 0;
    id0[2] = m40.z ? l40.z : 0;  id0[3] = m40.w ? l40.w : 0;
    id1[0] = m41.x ? l41.x : 0;  id1[1] = m41.y ? l41.y : 0;
    id1[2] = m41.z ? l41.z : 0;  id1[3] = m41.w ? l41.w : 0;
    int ix0[4], ix1[4];
#pragma unroll
    for (int j = 0; j < 4; ++j) {
        ix0[j] = id0[j] ? id0[j] - 1 : 0;
        ix1[j] = id1[j] ? id1[j] - 1 : 0;
    }

    const float (*mt)[SEGS + 1] = mtr[grp];
    float ss0[4] = {0.f, 0.f, 0.f, 0.f};
    float ss1[4] = {0.f, 0.f, 0.f, 0.f};
#pragma unroll
    for (int c = 0; c < CCH; ++c) {
#pragma unroll
        for (int j = 0; j < 4; ++j) {
            float d0 = ((const float*)&e0[c])[j] - mt[c][ix0[j]];
            ss0[j] += d0 * d0;
            float d1 = ((const float*)&e1[c])[j] - mt[c][ix1[j]];
            ss1[j] += d1 * d1;
        }
    }
    float* lp = &lpen[grp][0];
#pragma unroll
    for (int j = 0; j < 4; ++j) {
        if (id0[j]) {
            float d = sqrtf(fmaxf(ss0[j], 1e-12f));
            float h = fmaxf(d - 0.5f, 0.f);
            fadd(&lp[ix0[j]], h * h);
        }
        if (id1[j]) {
            float d = sqrtf(fmaxf(ss1[j], 1e-12f));
            float h = fmaxf(d - 0.5f, 0.f);
            fadd(&lp[ix1[j]], h * h);
        }
    }
    __syncthreads();
    if (threadIdx.x < SEGS) {
        const int s = threadIdx.x;
        float v = lpen[0][s] + lpen[1][s] + lpen[2][s] + lpen[3][s];
        if (v != 0.f) fadd(&ws[1152 + b * SEGS + s], v);
    }
}

__global__ __launch_bounds__(256) void finalize_kernel(
    const float* __restrict__ ws, float* __restrict__ out)
{
    __shared__ float cnt[BATCH][SEGS];
    __shared__ float mu[BATCH][SEGS][CCH];
    __shared__ float pen[BATCH][SEGS];
    __shared__ float res[BATCH][3];

    for (int i = threadIdx.x; i < BATCH * SEGS; i += 256) {
        (&cnt[0][0])[i] = ws[i];
        (&pen[0][0])[i] = ws[1152 + i];
    }
    for (int i = threadIdx.x; i < BATCH * SEGS * CCH; i += 256) {
        float c = ws[i / CCH];
        (&mu[0][0][0])[i] = ws[128 + i] / fmaxf(c, 1.0f);
    }
    __syncthreads();

    const int b = threadIdx.x >> 5;   // 8 batches x 32-lane groups
    const int l = threadIdx.x & 31;

    float pullv = 0.f, Kf = 0.f;
    if (l < SEGS && cnt[b][l] > 0.f) {
        Kf = 1.f;
        pullv = pen[b][l] / cnt[b][l];
    }
    float hs = 0.f, np = 0.f;
    for (int p = l; p < 256; p += 32) {
        int i = p >> 4, j = p & 15;
        if (i < j && cnt[b][i] > 0.f && cnt[b][j] > 0.f) {
            float ssq = 0.f;
#pragma unroll
            for (int c = 0; c < CCH; ++c) {
                float d = mu[b][i][c] - mu[b][j][c];
                ssq += d * d;
            }
            float dist = sqrtf(fmaxf(ssq, 1e-12f));
            float h = fmaxf(3.0f - dist, 0.f);   // 2*DELTA_D = 3.0
            hs += h * h;
            np += 1.f;
        }
    }
#pragma unroll
    for (int m = 16; m >= 1; m >>= 1) {
        pullv += __shfl_xor(pullv, m);
        Kf    += __shfl_xor(Kf, m);
        hs    += __shfl_xor(hs, m);
        np    += __shfl_xor(np, m);
    }
    if (l == 0) {
        res[b][0] = (Kf > 0.f) ? pullv / Kf : 0.f;
        res[b][1] = (np > 0.f) ? hs / np : 0.f;
        res[b][2] = (Kf > 0.f) ? 1.f : 0.f;
    }
    __syncthreads();
    if (threadIdx.x == 0) {
        float sp = 0.f, sh = 0.f, nv = 0.f;
        for (int bb = 0; bb < BATCH; ++bb) {
            sp += res[bb][0] * res[bb][2];
            sh += res[bb][1] * res[bb][2];
            nv += res[bb][2];
        }
        nv = fmaxf(nv, 1.f);
        out[0] = sp / nv;
        out[1] = sh / nv;
    }
}

extern "C" void kernel_launch(void* const* d_in, const int* in_sizes, int n_in,
                              void* d_out, int out_size, void* d_ws, size_t ws_size,
                              hipStream_t stream)
{
    const float* emb = (const float*)d_in[0];
    const int* lab = (const int*)d_in[1];
    const int* msk = (const int*)d_in[2];
    float* out = (float*)d_out;
    float* ws = (float*)d_ws;

    hipMemsetAsync(d_ws, 0, 1280 * sizeof(float), stream);
    dim3 grid(GX, BATCH);
    accum_kernel<<<grid, 256, 0, stream>>>(emb, lab, msk, ws);
    pull_kernel<<<grid, 256, 0, stream>>>(emb, lab, msk, ws);
    finalize_kernel<<<1, 256, 0, stream>>>(ws, out);
}